// Round 9
// baseline (554.828 us; speedup 1.0000x reference)
//
#include <hip/hip_runtime.h>
#include <hip/hip_bf16.h>

typedef __bf16 bf16_t;
typedef __attribute__((ext_vector_type(8))) __bf16 bf16x8;
typedef __attribute__((ext_vector_type(4))) float f32x4;

#define NBLK 256
#define THR  256
// 256 blocks * 392 = 100352 >= 100000
#define CHUNK 392

// ---------------- DIY grid barrier (all NBLK blocks resident) -------------
__device__ inline void grid_barrier(int* bar, int idx) {
    __syncthreads();
    __threadfence();                       // release block's writes device-wide
    if (threadIdx.x == 0) {
        __hip_atomic_fetch_add(&bar[idx], 1, __ATOMIC_RELEASE, __HIP_MEMORY_SCOPE_AGENT);
        while (__hip_atomic_load(&bar[idx], __ATOMIC_ACQUIRE, __HIP_MEMORY_SCOPE_AGENT) < NBLK)
            __builtin_amdgcn_s_sleep(2);
    }
    __syncthreads();
    __threadfence();                       // acquire side for all lanes
}

// ------- pack B[K,N] f32 -> bf16 MFMA fragments ---------------------------
__device__ inline void packB_one(const float* __restrict__ B, bf16_t* __restrict__ Bp,
                                 int N, int idx) {
    int j    = idx & 7;
    int lane = (idx >> 3) & 63;
    int st   = idx >> 9;
    int nt   = N >> 4;
    int s = st / nt, t = st - s * nt;
    int k = s * 32 + (lane >> 4) * 8 + j;
    int n = t * 16 + (lane & 15);
    Bp[idx] = (bf16_t)B[(size_t)k * N + n];
}

// ---------------- fused preprocessing mega-kernel -------------------------
// P0 zero deg/cursor + pack W1/W2 | P1 deg count | P2 dinv + 2-level scan ->
// rowPtr | P3 scatter edges {src,nrm} into CSR. Grid barriers between phases.
__global__ __launch_bounds__(THR) void k_prep(
        const int* __restrict__ src, const int* __restrict__ dst, int E, int n,
        int* __restrict__ deg, int* __restrict__ cursor, float* __restrict__ dinv,
        int* __restrict__ rowPtr, int* __restrict__ bsum, int* __restrict__ bar,
        const float* __restrict__ W1, bf16_t* __restrict__ Bp1,
        const float* __restrict__ W2, bf16_t* __restrict__ Bp2,
        int2* __restrict__ edata) {
    int b = blockIdx.x, t = threadIdx.x;
    int tid = b * THR + t;
    const int nthr = NBLK * THR;           // 65536
    // ---- P0: zero deg+cursor, pack weights ----
    for (int i = tid; i < n; i += nthr) { deg[i] = 0; cursor[i] = 0; }
    if (tid < 32768) packB_one(W1, Bp1, 128, tid);
    else if (tid < 32768 + 4096) packB_one(W2, Bp2, 32, tid - 32768);
    grid_barrier(bar, 0);
    // ---- P1: degree count ----
    for (int e = tid; e < E; e += nthr) atomicAdd(&deg[dst[e]], 1);
    grid_barrier(bar, 1);
    // ---- P2a: dinv + per-block partial sums (block covers CHUNK nodes) ----
    __shared__ int red[THR];
    __shared__ int sb[NBLK];
    int base = b * CHUNK + 2 * t;
    int d0 = 0, d1 = 0;
    if (2 * t < CHUNK) {
        if (base < n)     { d0 = deg[base];     dinv[base]     = rsqrtf((float)(d0 + 1)); }
        if (base + 1 < n) { d1 = deg[base + 1]; dinv[base + 1] = rsqrtf((float)(d1 + 1)); }
    }
    int pair = d0 + d1;
    red[t] = pair;
    __syncthreads();
    for (int dd = 1; dd < THR; dd <<= 1) {   // Hillis-Steele inclusive
        int u = (t >= dd) ? red[t - dd] : 0;
        __syncthreads();
        red[t] += u;
        __syncthreads();
    }
    int excl_t = red[t] - pair;              // exclusive prefix within block
    if (t == THR - 1) bsum[b] = red[THR - 1];
    grid_barrier(bar, 2);
    // ---- P2c: every block redundantly scans all block sums ----
    int bv = bsum[t];                        // NBLK == THR
    sb[t] = bv;
    __syncthreads();
    for (int dd = 1; dd < NBLK; dd <<= 1) {
        int u = (t >= dd) ? sb[t - dd] : 0;
        __syncthreads();
        sb[t] += u;
        __syncthreads();
    }
    if (b == 0 && t == 0) rowPtr[n] = sb[NBLK - 1];   // total = E
    int excl_b = (b == 0) ? 0 : sb[b - 1];
    int run = excl_b + excl_t;
    if (2 * t < CHUNK) {
        if (base < n)     rowPtr[base]     = run;
        if (base + 1 < n) rowPtr[base + 1] = run + d0;
    }
    grid_barrier(bar, 3);
    // ---- P3: scatter edges into CSR ----
    for (int e = tid; e < E; e += nthr) {
        int s = src[e], d = dst[e];
        int pos = rowPtr[d] + atomicAdd(&cursor[d], 1);
        int2 p; p.x = s; p.y = __float_as_int(dinv[s] * dinv[d]);
        edata[pos] = p;
    }
}

// ------- GEMM with packed B: one wave per 16-row strip, full N ------------
// MFMA 16x16x32 (HW-verified): A[m=lane&15][k=quad*8+j], D: col=lane&15,row=quad*4+reg
template <int KSTEPS, int NTILES>
__global__ __launch_bounds__(256) void k_gemm_pf32(
        const float* __restrict__ A, const bf16_t* __restrict__ Bp,
        bf16_t* __restrict__ C, int M) {
    int wave = (blockIdx.x * blockDim.x + threadIdx.x) >> 6;
    if (wave * 16 >= M) return;
    int lane = threadIdx.x & 63;
    int r16 = lane & 15, quad = lane >> 4;
    const int K = KSTEPS * 32, N = NTILES * 16;
    f32x4 acc[NTILES] = {};
    const float* arow = A + (size_t)(wave * 16 + r16) * K + quad * 8;
#pragma unroll
    for (int s = 0; s < KSTEPS; ++s) {
        const float* ap = arow + s * 32;
        bf16x8 a;
#pragma unroll
        for (int j = 0; j < 8; ++j) a[j] = (bf16_t)ap[j];
        const bf16_t* bp = Bp + ((size_t)(s * NTILES) * 64 + lane) * 8;
#pragma unroll
        for (int t = 0; t < NTILES; ++t) {
            bf16x8 bfrag = *(const bf16x8*)(bp + t * 512);
            acc[t] = __builtin_amdgcn_mfma_f32_16x16x32_bf16(a, bfrag, acc[t], 0, 0, 0);
        }
    }
#pragma unroll
    for (int t = 0; t < NTILES; ++t)
#pragma unroll
        for (int r = 0; r < 4; ++r)
            C[(size_t)(wave * 16 + quad * 4 + r) * N + t * 16 + r16] = (bf16_t)acc[t][r];
}

template <int KSTEPS, int NTILES>
__global__ __launch_bounds__(256) void k_gemm_pa16(
        const bf16_t* __restrict__ A, const bf16_t* __restrict__ Bp,
        bf16_t* __restrict__ C, int M) {
    int wave = (blockIdx.x * blockDim.x + threadIdx.x) >> 6;
    if (wave * 16 >= M) return;
    int lane = threadIdx.x & 63;
    int r16 = lane & 15, quad = lane >> 4;
    const int K = KSTEPS * 32, N = NTILES * 16;
    f32x4 acc[NTILES] = {};
    const bf16_t* arow = A + (size_t)(wave * 16 + r16) * K + quad * 8;
#pragma unroll
    for (int s = 0; s < KSTEPS; ++s) {
        bf16x8 a = *(const bf16x8*)(arow + s * 32);
        const bf16_t* bp = Bp + ((size_t)(s * NTILES) * 64 + lane) * 8;
#pragma unroll
        for (int t = 0; t < NTILES; ++t) {
            bf16x8 bfrag = *(const bf16x8*)(bp + t * 512);
            acc[t] = __builtin_amdgcn_mfma_f32_16x16x32_bf16(a, bfrag, acc[t], 0, 0, 0);
        }
    }
#pragma unroll
    for (int t = 0; t < NTILES; ++t)
#pragma unroll
        for (int r = 0; r < 4; ++r)
            C[(size_t)(wave * 16 + quad * 4 + r) * N + t * 16 + r16] = (bf16_t)acc[t][r];
}

// ------- layer-1 aggregate: 16 lanes x bf16x8, 4 parity streams, 2-unroll -
// (R7-proven) H[i] = relu( sum_e nrm*XW1[src] + dinv[i]^2*XW1[i] + b1 )
__global__ __launch_bounds__(256) void k_agg1(
        const int* __restrict__ rowPtr, const int2* __restrict__ edata,
        const bf16_t* __restrict__ XW1, const float* __restrict__ dinv,
        const float* __restrict__ b1, bf16_t* __restrict__ H, int n) {
    int wave = (blockIdx.x * blockDim.x + threadIdx.x) >> 6;
    if (wave >= n) return;
    int lane = threadIdx.x & 63;
    int fl = (lane & 15) << 3;   // 8 features
    int h  = lane >> 4;          // parity stream 0..3
    int r0 = rowPtr[wave], r1 = rowPtr[wave + 1];
    float a0[8] = {}, a1[8] = {};
    int k = r0 + h;
    for (; k + 4 < r1; k += 8) {          // 2 independent gathers in flight
        int2 e0 = edata[k], e1 = edata[k + 4];
        float w0 = __int_as_float(e0.y), w1 = __int_as_float(e1.y);
        bf16x8 x0 = *(const bf16x8*)(XW1 + ((size_t)e0.x << 7) + fl);
        bf16x8 x1 = *(const bf16x8*)(XW1 + ((size_t)e1.x << 7) + fl);
#pragma unroll
        for (int j = 0; j < 8; ++j) { a0[j] += (float)x0[j] * w0; a1[j] += (float)x1[j] * w1; }
    }
    if (k < r1) {
        int2 e0 = edata[k];
        float w0 = __int_as_float(e0.y);
        bf16x8 x0 = *(const bf16x8*)(XW1 + ((size_t)e0.x << 7) + fl);
#pragma unroll
        for (int j = 0; j < 8; ++j) a0[j] += (float)x0[j] * w0;
    }
#pragma unroll
    for (int j = 0; j < 8; ++j) {        // convergent reduction over 4 streams
        a0[j] += a1[j];
        a0[j] += __shfl_xor(a0[j], 16);
        a0[j] += __shfl_xor(a0[j], 32);
    }
    if (h == 0) {
        float d = dinv[wave], d2 = d * d;
        bf16x8 xs = *(const bf16x8*)(XW1 + ((size_t)wave << 7) + fl);
        bf16x8 hv;
#pragma unroll
        for (int j = 0; j < 8; ++j) {
            float v = a0[j] + (float)xs[j] * d2 + b1[fl + j];
            hv[j] = (bf16_t)fmaxf(v, 0.f);
        }
        *(bf16x8*)(H + ((size_t)wave << 7) + fl) = hv;
    }
}

// ------- layer-2 aggregate + log_softmax (R7-proven) ----------------------
__global__ __launch_bounds__(256) void k_agg2(
        const int* __restrict__ rowPtr, const int2* __restrict__ edata,
        const bf16_t* __restrict__ XW2, const float* __restrict__ dinv,
        const float* __restrict__ b2, float* __restrict__ out, int n) {
    int wave = (blockIdx.x * blockDim.x + threadIdx.x) >> 6;
    if (wave >= n) return;
    int lane = threadIdx.x & 63;
    int f = lane & 31, h = lane >> 5;
    int r0 = rowPtr[wave], r1 = rowPtr[wave + 1];
    float acc0 = 0.f, acc1 = 0.f;
    int k = r0 + h;
    for (; k + 2 < r1; k += 4) {
        int2 e0 = edata[k], e1 = edata[k + 2];
        acc0 += (float)XW2[((size_t)e0.x << 5) + f] * __int_as_float(e0.y);
        acc1 += (float)XW2[((size_t)e1.x << 5) + f] * __int_as_float(e1.y);
    }
    if (k < r1) {
        int2 e0 = edata[k];
        acc0 += (float)XW2[((size_t)e0.x << 5) + f] * __int_as_float(e0.y);
    }
    float acc = acc0 + acc1;
    acc += __shfl_xor(acc, 32);          // convergent: combine the 2 streams
    float d = dinv[wave];
    float v = acc + (float)XW2[((size_t)wave << 5) + f] * d * d + b2[f];
    float mx = v;
#pragma unroll
    for (int m = 16; m >= 1; m >>= 1) mx = fmaxf(mx, __shfl_xor(mx, m));
    float s = expf(v - mx);
#pragma unroll
    for (int m = 16; m >= 1; m >>= 1) s += __shfl_xor(s, m);
    if (lane < 32) out[((size_t)wave << 5) + f] = v - mx - logf(s);
}

extern "C" void kernel_launch(void* const* d_in, const int* in_sizes, int n_in,
                              void* d_out, int out_size, void* d_ws, size_t ws_size,
                              hipStream_t stream) {
    const float* feat = (const float*)d_in[0];
    const int*   eidx = (const int*)d_in[1];
    const float* W1   = (const float*)d_in[2];
    const float* b1   = (const float*)d_in[3];
    const float* W2   = (const float*)d_in[4];
    const float* b2   = (const float*)d_in[5];
    float* out = (float*)d_out;

    const int FIN = 256, HID = 128, NCLS = 32;
    const int N = in_sizes[0] / FIN;   // 100000
    const int E = in_sizes[1] / 2;     // 800000
    const int* src = eidx;
    const int* dst = eidx + E;

    // workspace carve-up (256B aligned)
    char* ws = (char*)d_ws;
    size_t o = 0;
    auto alloc = [&](size_t bytes) -> void* {
        void* p = ws + o;
        o = (o + bytes + 255) & ~(size_t)255;
        return p;
    };
    int*    deg    = (int*)   alloc((size_t)N * 4);
    int*    cursor = (int*)   alloc((size_t)N * 4);
    float*  dinv   = (float*) alloc((size_t)N * 4);
    int*    rowPtr = (int*)   alloc((size_t)(N + 1) * 4);
    int*    bsum   = (int*)   alloc(NBLK * 4);
    int*    bar    = (int*)   alloc(256);                  // 4 barrier counters
    bf16_t* Bp1    = (bf16_t*)alloc((size_t)(FIN / 32) * (HID / 16) * 512 * 2); // 64 KB
    bf16_t* Bp2    = (bf16_t*)alloc((size_t)(HID / 32) * (NCLS / 16) * 512 * 2); // 8 KB
    int2*   edata  = (int2*)  alloc((size_t)E * 8);        // 6.4 MB
    bf16_t* XW1    = (bf16_t*)alloc((size_t)N * HID * 2);  // 25.6 MB
    bf16_t* H      = (bf16_t*)alloc((size_t)N * HID * 2);  // 25.6 MB
    bf16_t* XW2    = XW1;   // alias: XW1 dead after k_agg1

    const int T = 256;
    hipMemsetAsync(bar, 0, 16, stream);
    k_prep<<<NBLK, THR, 0, stream>>>(src, dst, E, N, deg, cursor, dinv,
                                     rowPtr, bsum, bar, W1, Bp1, W2, Bp2, edata);

    // layer 1: XW1 = bf16(feat @ W1)   (wave = 16 rows x 128 cols)
    {
        int waves = (N + 15) / 16;
        k_gemm_pf32<8, 8><<<(waves * 64 + T - 1) / T, T, 0, stream>>>(feat, Bp1, XW1, N);
    }
    k_agg1<<<(N * 64 + T - 1) / T, T, 0, stream>>>(rowPtr, edata, XW1, dinv, b1, H, N);

    // layer 2: XW2 = bf16(H @ W2)      (wave = 16 rows x 32 cols)
    {
        int waves = (N + 15) / 16;
        k_gemm_pa16<4, 2><<<(waves * 64 + T - 1) / T, T, 0, stream>>>(H, Bp2, XW2, N);
    }
    k_agg2<<<(N * 64 + T - 1) / T, T, 0, stream>>>(rowPtr, edata, XW2, dinv, b2, out, N);
}